// Round 5
// baseline (398.025 us; speedup 1.0000x reference)
//
#include <hip/hip_runtime.h>
#include <stdint.h>
#include <math.h>

// Problem constants (hard-coded in reference)
#define NBBOX 8192
#define FDIM  4096
#define H1DIM 64
#define H2DIM 32
#define NW    16
#define NCOL  1024   // NW * H1DIM

typedef __attribute__((ext_vector_type(8))) _Float16 f16x8;
typedef __attribute__((ext_vector_type(4))) float    f32x4;

typedef __attribute__((address_space(1))) void* gptr_t;
typedef __attribute__((address_space(3))) void* lptr_t;

// async global->LDS, 16B per lane; LDS dest is wave-uniform base + lane*16
__device__ __forceinline__ void g2l16(const void* g, void* l) {
    __builtin_amdgcn_global_load_lds((gptr_t)(uintptr_t)g,
                                     (lptr_t)(uint32_t)(uintptr_t)l,
                                     16, 0, 0);
}

// ---------------- kernel 1: prep = gather_w (blocks 0..511) + convert_x (rest) ----------------
__global__ __launch_bounds__(256) void prep(
    const float* __restrict__ x, _Float16* __restrict__ xh,
    const float* __restrict__ W1, const int* __restrict__ words,
    uint32_t* __restrict__ bth_u32)
{
    __shared__ uint32_t t[64 * 69];   // gather transpose tile, pad 69 -> conflict-free
    if (blockIdx.x >= 512) {
        // ---- convert x fp32 -> fp16, 8 elems/thread ----
        int gid = (blockIdx.x - 512) * 256 + threadIdx.x;
        int idx = gid * 8;
        float4 a = *(const float4*)(x + idx);
        float4 b = *(const float4*)(x + idx + 4);
        f16x8 h;
        h[0] = (_Float16)a.x; h[1] = (_Float16)a.y; h[2] = (_Float16)a.z; h[3] = (_Float16)a.w;
        h[4] = (_Float16)b.x; h[5] = (_Float16)b.y; h[6] = (_Float16)b.z; h[7] = (_Float16)b.w;
        *(f16x8*)(xh + idx) = h;
        return;
    }
    // ---- gather+transpose W1[words] -> Bt[1024][4096] fp16, coalesced both sides ----
    const int wi = blockIdx.x >> 5;
    const int ft = blockIdx.x & 31;
    const int f0 = ft * 128;
    const int w  = words[wi];
    const int tid  = threadIdx.x;
    const int c    = tid & 63;
    const int fgrp = tid >> 6;       // 0..3

    const float* src = W1 + ((size_t)w * FDIM + f0) * H1DIM + c;
#pragma unroll
    for (int p = 0; p < 16; ++p) {
        const int f = fgrp * 2 + p * 8;          // even f in 0..126
        float v0 = src[(size_t)f * H1DIM];        // coalesced (c contiguous)
        float v1 = src[(size_t)(f + 1) * H1DIM];
        union { _Float16 h[2]; uint32_t u; } pk;
        pk.h[0] = (_Float16)v0; pk.h[1] = (_Float16)v1;
        t[c * 69 + (f >> 1)] = pk.u;
    }
    __syncthreads();
#pragma unroll
    for (int p = 0; p < 16; ++p) {
        const int cc = p * 4 + (tid >> 6);
        const int fd = tid & 63;
        bth_u32[(size_t)(wi * 64 + cc) * (FDIM / 2) + ft * 64 + fd] = t[cc * 69 + fd];
    }
}

// ---------------- kernel 2: GEMM layer1 + fused layer2/3 + sigmoid ----------------
// 128x128 tile, 512 threads = 8 waves (4x2 grid, 32x64 quadrant each), BK=128 as
// 4 packed 32-panels, round-2-style 2-barrier K-loop (32 iters). Each wave's
// quadrant = one word x 32 rows -> fp32 LDS round-trip (XOR swizzle), fp32 VALU
// layer2/3 + sigmoid -> sig. 16 waves/CU (4/SIMD) for latency hiding.
__global__ __launch_bounds__(512, 4) void gemm_fused(
    const _Float16* __restrict__ xh, const _Float16* __restrict__ bth,
    const int* __restrict__ words, const float* __restrict__ b1,
    const float* __restrict__ W2, const float* __restrict__ b2,
    const float* __restrict__ W3, const float* __restrict__ b3,
    float* __restrict__ sig)   // [NW][NBBOX]
{
    // 64 KB: staging A panels [0,16K) halves, B panels [16K,32K); epilogue
    // reuses the whole array as 8 x 2048-float wave-private tiles.
    __shared__ __align__(16) _Float16 smem[32768];

    const int mt   = blockIdx.x >> 3;   // 64 M-tiles
    const int nt   = blockIdx.x & 7;    // 8 N-tiles
    const int t    = threadIdx.x;
    const int w    = t >> 6;            // 0..7
    const int lane = t & 63;
    const int m0 = mt * 128, n0 = nt * 128;

    f32x4 acc[2][4] = {};               // 32x64 quadrant

    const int rs = w * 16 + (lane >> 2);     // staging row 0..127 (8 waves cover all)
    const int kc = (lane & 3) * 8;

    const _Float16* A = xh  + (size_t)m0 * FDIM;
    const _Float16* B = bth + (size_t)n0 * FDIM;

    const int wm = w >> 1, wn = w & 1;       // wave grid 4x2
    const int ml = lane & 15;
    const int q8 = (lane >> 4) * 8;

    for (int kt = 0; kt < 32; ++kt) {
        const int k0 = kt * 128;
#pragma unroll
        for (int s = 0; s < 4; ++s) {        // stage 4 panels of 32-K
            const int kp = k0 + s * 32 + kc;
            g2l16(A + (size_t)rs * FDIM + kp, smem + s * 4096 + w * 512);
            g2l16(B + (size_t)rs * FDIM + kp, smem + 16384 + s * 4096 + w * 512);
        }
        __syncthreads();                     // drain staging

#pragma unroll
        for (int s = 0; s < 4; ++s) {
            const _Float16* Ap = smem + s * 4096;
            const _Float16* Bp = smem + 16384 + s * 4096;
            f16x8 af[2], bfr[4];
#pragma unroll
            for (int i = 0; i < 2; ++i)
                af[i] = *(const f16x8*)&Ap[(wm * 32 + i * 16 + ml) * 32 + q8];
#pragma unroll
            for (int j = 0; j < 4; ++j)
                bfr[j] = *(const f16x8*)&Bp[(wn * 64 + j * 16 + ml) * 32 + q8];
#pragma unroll
            for (int i = 0; i < 2; ++i)
#pragma unroll
                for (int j = 0; j < 4; ++j)
                    acc[i][j] = __builtin_amdgcn_mfma_f32_16x16x32_f16(af[i], bfr[j], acc[i][j], 0, 0, 0);
        }
        __syncthreads();                     // LDS WAR before next stage / epilogue
    }

    // ---- epilogue: this wave's quadrant = word (nt*2+wn), rows m0+wm*32..+31 ----
    const int word = nt * 2 + wn;
    const int wv   = words[word];
    float* tilef = (float*)smem + w * 2048;  // 8 KB/wave: 32 rows x 64 f32, XOR-swizzled

    // C/D layout: col=lane&15 (ml), row=quad*4+reg  [m89-verified]
    const int q = lane >> 4;
#pragma unroll
    for (int j = 0; j < 4; ++j) {
        const float bias = b1[wv * H1DIM + j * 16 + ml];
#pragma unroll
        for (int i = 0; i < 2; ++i)
#pragma unroll
            for (int r = 0; r < 4; ++r) {
                float v = acc[i][j][r] + bias;
                v = v > 0.f ? v : 0.f;                    // relu(h1), fp32
                const int row   = i * 16 + q * 4 + r;     // 0..31
                const int chunk = j * 4 + (ml >> 2);      // logical col chunk
                const int phys  = chunk ^ (row & 15);     // swizzle
                tilef[row * 64 + phys * 4 + (ml & 3)] = v;
            }
    }
    // tile is wave-private; compiler inserts lgkmcnt waits for write->read dependence

    const float* W2w = W2 + (size_t)wv * (H1DIM * H2DIM);   // wave-uniform -> s_load
    const int row = lane & 31;               // lanes 32..63 duplicate rows (broadcast reads)
    float acc2[H2DIM];
#pragma unroll
    for (int j = 0; j < H2DIM; ++j) acc2[j] = 0.f;

#pragma unroll
    for (int c = 0; c < 16; ++c) {
        const int phys = c ^ (row & 15);
        f32x4 h = *(const f32x4*)&tilef[row * 64 + phys * 4];
#pragma unroll
        for (int kk = 0; kk < 4; ++kk) {
            const float hv = h[kk];
            const int k = c * 4 + kk;
#pragma unroll
            for (int j = 0; j < H2DIM; ++j)
                acc2[j] = fmaf(hv, W2w[k * H2DIM + j], acc2[j]);
        }
    }

    float logit = b3[wv];
#pragma unroll
    for (int j = 0; j < H2DIM; ++j) {
        float h2 = acc2[j] + b2[wv * H2DIM + j];
        h2 = h2 > 0.f ? h2 : 0.f;
        logit = fmaf(h2, W3[wv * H2DIM + j], logit);
    }
    if (lane < 32)
        sig[(size_t)word * NBBOX + m0 + wm * 32 + row] = 1.f / (1.f + expf(-logit));
}

// ---------------- kernel 3: product over words ----------------
__global__ void prod_k(const float* __restrict__ sig, float* __restrict__ out) {
    const int r = blockIdx.x * 256 + threadIdx.x;
    float p = 1.f;
#pragma unroll
    for (int wi = 0; wi < NW; ++wi) p *= sig[(size_t)wi * NBBOX + r];
    out[r] = p;
}

extern "C" void kernel_launch(void* const* d_in, const int* in_sizes, int n_in,
                              void* d_out, int out_size, void* d_ws, size_t ws_size,
                              hipStream_t stream)
{
    const float* x   = (const float*)d_in[1];
    const int* words = (const int*)  d_in[2];
    const float* W1  = (const float*)d_in[3];
    const float* b1  = (const float*)d_in[4];
    const float* W2  = (const float*)d_in[5];
    const float* b2  = (const float*)d_in[6];
    const float* W3  = (const float*)d_in[7];
    const float* b3  = (const float*)d_in[8];
    float* out = (float*)d_out;

    char* ws = (char*)d_ws;
    _Float16* xh  = (_Float16*)(ws);                         // 8192*4096*2  = 64 MiB
    _Float16* bth = (_Float16*)(ws + 67108864);              // 1024*4096*2  = 8 MiB
    float*    sig = (float*)   (ws + 67108864 + 8388608);    // 16*8192*4    = 512 KiB

    prep<<<512 + NBBOX * FDIM / 8 / 256, 256, 0, stream>>>(x, xh, W1, words, (uint32_t*)bth);
    gemm_fused<<<512, 512, 0, stream>>>(xh, bth, words, b1, W2, b2, W3, b3, sig);
    prod_k<<<NBBOX / 256, 256, 0, stream>>>(sig, out);
}

// Round 6
// 342.271 us; speedup vs baseline: 1.1629x; 1.1629x over previous
//
#include <hip/hip_runtime.h>
#include <stdint.h>
#include <math.h>

// Problem constants (hard-coded in reference)
#define NBBOX 8192
#define FDIM  4096
#define H1DIM 64
#define H2DIM 32
#define NW    16
#define NCOL  1024   // NW * H1DIM

typedef __attribute__((ext_vector_type(8))) _Float16 f16x8;
typedef __attribute__((ext_vector_type(4))) float    f32x4;

typedef __attribute__((address_space(1))) void* gptr_t;
typedef __attribute__((address_space(3))) void* lptr_t;

// async global->LDS, 16B per lane; LDS dest is wave-uniform base + lane*16
__device__ __forceinline__ void g2l16(const void* g, void* l) {
    __builtin_amdgcn_global_load_lds((gptr_t)(uintptr_t)g,
                                     (lptr_t)(uint32_t)(uintptr_t)l,
                                     16, 0, 0);
}

// ---------------- kernel 1: prep = gather_w (blocks 0..511) + convert_x (rest) ----------------
__global__ __launch_bounds__(256) void prep(
    const float* __restrict__ x, _Float16* __restrict__ xh,
    const float* __restrict__ W1, const int* __restrict__ words,
    uint32_t* __restrict__ bth_u32)
{
    __shared__ uint32_t t[64 * 69];   // gather transpose tile, pad 69 -> conflict-free
    if (blockIdx.x >= 512) {
        // ---- convert x fp32 -> fp16, 8 elems/thread ----
        int gid = (blockIdx.x - 512) * 256 + threadIdx.x;
        int idx = gid * 8;
        float4 a = *(const float4*)(x + idx);
        float4 b = *(const float4*)(x + idx + 4);
        f16x8 h;
        h[0] = (_Float16)a.x; h[1] = (_Float16)a.y; h[2] = (_Float16)a.z; h[3] = (_Float16)a.w;
        h[4] = (_Float16)b.x; h[5] = (_Float16)b.y; h[6] = (_Float16)b.z; h[7] = (_Float16)b.w;
        *(f16x8*)(xh + idx) = h;
        return;
    }
    // ---- gather+transpose W1[words] -> Bt[1024][4096] fp16, coalesced both sides ----
    const int wi = blockIdx.x >> 5;
    const int ft = blockIdx.x & 31;
    const int f0 = ft * 128;
    const int w  = words[wi];
    const int tid  = threadIdx.x;
    const int c    = tid & 63;
    const int fgrp = tid >> 6;       // 0..3

    const float* src = W1 + ((size_t)w * FDIM + f0) * H1DIM + c;
#pragma unroll
    for (int p = 0; p < 16; ++p) {
        const int f = fgrp * 2 + p * 8;          // even f in 0..126
        float v0 = src[(size_t)f * H1DIM];        // coalesced (c contiguous)
        float v1 = src[(size_t)(f + 1) * H1DIM];
        union { _Float16 h[2]; uint32_t u; } pk;
        pk.h[0] = (_Float16)v0; pk.h[1] = (_Float16)v1;
        t[c * 69 + (f >> 1)] = pk.u;
    }
    __syncthreads();
#pragma unroll
    for (int p = 0; p < 16; ++p) {
        const int cc = p * 4 + (tid >> 6);
        const int fd = tid & 63;
        bth_u32[(size_t)(wi * 64 + cc) * (FDIM / 2) + ft * 64 + fd] = t[cc * 69 + fd];
    }
}

// ---------------- kernel 2: GEMM layer1 + fused layer2/3 + sigmoid ----------------
// Round-2 proven K-loop: 128x128 tile, 256 thr = 4 waves (2x2, 64x64 quadrant),
// BK=64 as 2 packed 32-panels, 2 barriers/iter, no dbuf (r4 dbuf and r5 512-thr
// both regressed). XCD-aware decode: mt = bx&63, nt = bx>>6 puts all 8 blocks
// sharing an A-slice on ONE XCD (XCD=bx%8=mt%8) -> A read once per XCD.
// Fused epilogue (r4): wave quadrant = one word x 64 rows, fp32 LDS round-trip,
// VALU layer2/3 + sigmoid -> sig.
__global__ __launch_bounds__(256, 2) void gemm_fused(
    const _Float16* __restrict__ xh, const _Float16* __restrict__ bth,
    const int* __restrict__ words, const float* __restrict__ b1,
    const float* __restrict__ W2, const float* __restrict__ b2,
    const float* __restrict__ W3, const float* __restrict__ b3,
    float* __restrict__ sig)   // [NW][NBBOX]
{
    // 64 KB: staging uses first 32 KB (A panels [0,8K), B panels [8K,16K) halves);
    // epilogue reuses all 64 KB as 4 x 4096-float wave-private tiles.
    __shared__ __align__(16) _Float16 smem[32768];

    const int mt   = blockIdx.x & 63;   // 64 M-tiles; same-mt blocks share XCD
    const int nt   = blockIdx.x >> 6;   // 8 N-tiles
    const int t    = threadIdx.x;
    const int w    = t >> 6;
    const int lane = t & 63;
    const int m0 = mt * 128, n0 = nt * 128;

    f32x4 acc[4][4] = {};

    const int rs = w * 16 + (lane >> 2);
    const int kc = (lane & 3) * 8;

    const _Float16* A = xh  + (size_t)m0 * FDIM;
    const _Float16* B = bth + (size_t)n0 * FDIM;

    const int wm = w >> 1, wn = w & 1;
    const int ml = lane & 15;
    const int q8 = (lane >> 4) * 8;

    for (int kt = 0; kt < 64; ++kt) {
        const int k0 = kt * 64;
#pragma unroll
        for (int s = 0; s < 2; ++s) {
            _Float16* Ap = smem + s * 4096;
            _Float16* Bp = smem + 8192 + s * 4096;
            const int kp = k0 + s * 32 + kc;
            g2l16(A + (size_t)rs * FDIM + kp,        Ap + w * 512);
            g2l16(A + (size_t)(rs + 64) * FDIM + kp, Ap + 2048 + w * 512);
            g2l16(B + (size_t)rs * FDIM + kp,        Bp + w * 512);
            g2l16(B + (size_t)(rs + 64) * FDIM + kp, Bp + 2048 + w * 512);
        }
        __syncthreads();   // drains staging vmcnt + barrier

#pragma unroll
        for (int s = 0; s < 2; ++s) {
            const _Float16* Ap = smem + s * 4096;
            const _Float16* Bp = smem + 8192 + s * 4096;
            f16x8 af[4], bfr[4];
#pragma unroll
            for (int i = 0; i < 4; ++i)
                af[i] = *(const f16x8*)&Ap[(wm * 64 + i * 16 + ml) * 32 + q8];
#pragma unroll
            for (int j = 0; j < 4; ++j)
                bfr[j] = *(const f16x8*)&Bp[(wn * 64 + j * 16 + ml) * 32 + q8];
#pragma unroll
            for (int i = 0; i < 4; ++i)
#pragma unroll
                for (int j = 0; j < 4; ++j)
                    acc[i][j] = __builtin_amdgcn_mfma_f32_16x16x32_f16(af[i], bfr[j], acc[i][j], 0, 0, 0);
        }
        __syncthreads();   // LDS WAR before next stage / epilogue
    }

    // ---- epilogue: this wave's quadrant = word (nt*2+wn), rows m0+wm*64..+63 ----
    const int word = nt * 2 + wn;
    const int wv   = words[word];
    float* tilef = (float*)smem + w * 4096;   // 16 KB/wave: 64 rows x 64 f32, XOR-swizzled

    // C/D layout: col=lane&15 (ml), row=quad*4+reg  [m89-verified]
    const int q = lane >> 4;
#pragma unroll
    for (int j = 0; j < 4; ++j) {
        const float bias = b1[wv * H1DIM + j * 16 + ml];
#pragma unroll
        for (int i = 0; i < 4; ++i)
#pragma unroll
            for (int r = 0; r < 4; ++r) {
                float v = acc[i][j][r] + bias;
                v = v > 0.f ? v : 0.f;                    // relu(h1), fp32
                const int row   = i * 16 + q * 4 + r;
                const int chunk = j * 4 + (ml >> 2);      // logical col chunk
                const int phys  = chunk ^ (row & 15);     // swizzle
                tilef[row * 64 + phys * 4 + (ml & 3)] = v;
            }
    }
    // tile is wave-private; compiler inserts lgkmcnt waits for write->read dependence

    const float* W2w = W2 + (size_t)wv * (H1DIM * H2DIM);   // wave-uniform -> s_load
    float acc2[H2DIM];
#pragma unroll
    for (int j = 0; j < H2DIM; ++j) acc2[j] = 0.f;

#pragma unroll
    for (int c = 0; c < 16; ++c) {
        const int phys = c ^ (lane & 15);                 // row = lane
        f32x4 h = *(const f32x4*)&tilef[lane * 64 + phys * 4];
#pragma unroll
        for (int kk = 0; kk < 4; ++kk) {
            const float hv = h[kk];
            const int k = c * 4 + kk;
#pragma unroll
            for (int j = 0; j < H2DIM; ++j)
                acc2[j] = fmaf(hv, W2w[k * H2DIM + j], acc2[j]);
        }
    }

    float logit = b3[wv];
#pragma unroll
    for (int j = 0; j < H2DIM; ++j) {
        float h2 = acc2[j] + b2[wv * H2DIM + j];
        h2 = h2 > 0.f ? h2 : 0.f;
        logit = fmaf(h2, W3[wv * H2DIM + j], logit);
    }
    sig[(size_t)word * NBBOX + m0 + wm * 64 + lane] = 1.f / (1.f + expf(-logit));
}

// ---------------- kernel 3: product over words ----------------
__global__ void prod_k(const float* __restrict__ sig, float* __restrict__ out) {
    const int r = blockIdx.x * 256 + threadIdx.x;
    float p = 1.f;
#pragma unroll
    for (int wi = 0; wi < NW; ++wi) p *= sig[(size_t)wi * NBBOX + r];
    out[r] = p;
}

extern "C" void kernel_launch(void* const* d_in, const int* in_sizes, int n_in,
                              void* d_out, int out_size, void* d_ws, size_t ws_size,
                              hipStream_t stream)
{
    const float* x   = (const float*)d_in[1];
    const int* words = (const int*)  d_in[2];
    const float* W1  = (const float*)d_in[3];
    const float* b1  = (const float*)d_in[4];
    const float* W2  = (const float*)d_in[5];
    const float* b2  = (const float*)d_in[6];
    const float* W3  = (const float*)d_in[7];
    const float* b3  = (const float*)d_in[8];
    float* out = (float*)d_out;

    char* ws = (char*)d_ws;
    _Float16* xh  = (_Float16*)(ws);                         // 8192*4096*2  = 64 MiB
    _Float16* bth = (_Float16*)(ws + 67108864);              // 1024*4096*2  = 8 MiB
    float*    sig = (float*)   (ws + 67108864 + 8388608);    // 16*8192*4    = 512 KiB

    prep<<<512 + NBBOX * FDIM / 8 / 256, 256, 0, stream>>>(x, xh, W1, words, (uint32_t*)bth);
    gemm_fused<<<512, 256, 0, stream>>>(xh, bth, words, b1, W2, b2, W3, b3, sig);
    prod_k<<<NBBOX / 256, 256, 0, stream>>>(sig, out);
}